// Round 9
// baseline (369.062 us; speedup 1.0000x reference)
//
#include <hip/hip_runtime.h>

#define T_HORIZON 50
#define NU 4
#define NY 4
#define KH 32
#define BPB 128                   // batch elements per block: 2 per lane (.x=b, .y=b+64)

typedef float v2f __attribute__((ext_vector_type(2)));

__device__ __forceinline__ v2f fma2(v2f a, v2f b, v2f c) {
    return __builtin_elementwise_fma(a, b, c);   // per-element IEEE fma
}
__device__ __forceinline__ v2f splat(float s) { return v2f{s, s}; }

#define TANH_SCALE 2.88539008177792681472f

// Stage transposed weights into d_ws: ws[jg][i][k] = W_all[i][jg + 4k]
// i=0..7: Wh rows; i=8: bh; i=9: wor. 4*10*8 = 320 floats.
__global__ void stage_weights(const float* __restrict__ Whg,
                              const float* __restrict__ bhg,
                              const float* __restrict__ Wog,
                              float* __restrict__ ws) {
    int idx = threadIdx.x;
    if (idx < 320) {
        int jg = idx / 80, r = idx % 80, i = r / 8, k = r % 8;
        int j = jg + 4 * k;
        float v = (i < 8) ? Whg[i * KH + j] : (i == 8 ? bhg[j] : Wog[j]);
        ws[idx] = v;
    }
}

__global__ __launch_bounds__(256, 4) void rollout_kernel(
    const float* __restrict__ u,    // (B, 50, 4)
    const float* __restrict__ y0g,  // (B, 4)
    const float* __restrict__ bog,  // (1)
    const float* __restrict__ wsW,  // (4, 10, 8) staged
    float* __restrict__ out)        // (B, 50, 1)
{
    __shared__ __align__(16) float sOut[BPB * T_HORIZON];  // 25.6 KB
    __shared__ v2f sRed[2][4][64];                         // 4 KB, dbuf partials

    const int tid  = threadIdx.x;
    const int lane = tid & 63;
    const int jg = __builtin_amdgcn_readfirstlane(tid >> 6);

    const float* wb = wsW + jg * 80;   // uniform base
    // Wave-uniform scalar weights -> SGPRs (splat at use via op_sel).
    float wh[8][8], wor[8];
#pragma unroll
    for (int i = 0; i < 8; ++i)
#pragma unroll
        for (int k = 0; k < 8; ++k)
            wh[i][k] = wb[i * 8 + k];
#pragma unroll
    for (int k = 0; k < 8; ++k) wor[k] = wb[9 * 8 + k];
    const float bor = bog[0];

    // bh: VGPR src2 of the first fma (one SGPR operand already used by wh).
    // Scalar 32-bit pins (proven safe r6/r7/r8) keep them VGPR-resident.
    float bhs[8];
#pragma unroll
    for (int k = 0; k < 8; ++k) bhs[k] = wb[8 * 8 + k];
#pragma unroll
    for (int k = 0; k < 8; ++k) asm volatile("" : "+v"(bhs[k]));

    const v2f scale2 = {TANH_SCALE, TANH_SCALE};
    const v2f one2   = {1.0f, 1.0f};
    const v2f ntwo2  = {-2.0f, -2.0f};

    // Two real batch elements per lane: bA (.x) and bB = bA+64 (.y).
    const int bA = blockIdx.x * BPB + lane;
    const int bB = bA + 64;
    const float4* ubA = (const float4*)(u + (size_t)bA * T_HORIZON * NU);
    const float4* ubB = (const float4*)(u + (size_t)bB * T_HORIZON * NU);
    float4 yA = *(const float4*)(y0g + (size_t)bA * NY);
    float4 yB = *(const float4*)(y0g + (size_t)bB * NY);
    v2f py1 = {yA.x, yB.x}, py2 = {yA.y, yB.y}, py3 = {yA.z, yB.z}, py4 = {yA.w, yB.w};

    float4 unA = ubA[0], unB = ubB[0];
    for (int t = 0; t < T_HORIZON; ++t) {
        float4 uA = unA, uB = unB;
        if (t + 1 < T_HORIZON) { unA = ubA[t + 1]; unB = ubB[t + 1]; }

        v2f ux = {uA.x, uB.x}, uy = {uA.y, uB.y}, uz = {uA.z, uB.z}, uw = {uA.w, uB.w};

        v2f pcls = {0.0f, 0.0f};
#pragma unroll
        for (int k = 0; k < 8; ++k) {   // j = jg + 4k, ascending (r2/r4/r7/r8 order)
            // identical element order: bh, u0..u3, y1..y4
            v2f a = fma2(ux, splat(wh[0][k]), v2f{bhs[k], bhs[k]});
            a = fma2(uy,  splat(wh[1][k]), a);
            a = fma2(uz,  splat(wh[2][k]), a);
            a = fma2(uw,  splat(wh[3][k]), a);
            a = fma2(py1, splat(wh[4][k]), a);
            a = fma2(py2, splat(wh[5][k]), a);
            a = fma2(py3, splat(wh[6][k]), a);
            a = fma2(py4, splat(wh[7][k]), a);

            // tanh cluster, per-element identical to rounds 2..8
            v2f s = a * scale2;
            float e0 = __builtin_amdgcn_exp2f(s.x);
            float e1 = __builtin_amdgcn_exp2f(s.y);
            v2f ep = v2f{e0, e1} + one2;
            v2f r  = {__builtin_amdgcn_rcpf(ep.x), __builtin_amdgcn_rcpf(ep.y)};
            v2f th = fma2(ntwo2, r, one2);
            v2f m  = th * splat(wor[k]);
            pcls += m;                   // per-component serial sum, k ascending
        }

        // Cross-wave class reduce: double-buffered, ONE barrier per step.
        const int buf = t & 1;
        sRed[buf][jg][lane] = pcls;
        __syncthreads();
        v2f c0 = sRed[buf][0][lane];
        v2f c1 = sRed[buf][1][lane];
        v2f c2 = sRed[buf][2][lane];
        v2f c3 = sRed[buf][3][lane];
        v2f partial = (c0 + c1) + (c2 + c3);   // same grouping as shfl version
        v2f pred = v2f{bor, bor} + partial;

        if (jg == 0) {
            sOut[lane * T_HORIZON + t]        = pred.x;
            sOut[(lane + 64) * T_HORIZON + t] = pred.y;
        }

        py4 = py3; py3 = py2; py2 = py1; py1 = pred;
    }
    __syncthreads();

    // Coalesced flush: block's out region is contiguous 128*50 floats.
    const float4* s4 = (const float4*)sOut;
    float4* o4 = (float4*)(out + (size_t)blockIdx.x * BPB * T_HORIZON);
#pragma unroll
    for (int k = 0; k < 7; ++k) {
        int idx = k * 256 + tid;
        if (idx < (BPB * T_HORIZON) / 4) o4[idx] = s4[idx];
    }
}

extern "C" void kernel_launch(void* const* d_in, const int* in_sizes, int n_in,
                              void* d_out, int out_size, void* d_ws, size_t ws_size,
                              hipStream_t stream) {
    const float* u   = (const float*)d_in[0];
    const float* y0g = (const float*)d_in[1];
    const float* Whg = (const float*)d_in[2];
    const float* bhg = (const float*)d_in[3];
    const float* Wog = (const float*)d_in[4];
    const float* bog = (const float*)d_in[5];
    float* out = (float*)d_out;
    float* ws  = (float*)d_ws;    // 320 floats staged weights

    stage_weights<<<1, 320, 0, stream>>>(Whg, bhg, Wog, ws);

    const int B = in_sizes[1] / NY;          // 524288
    dim3 grid(B / BPB), block(256);
    rollout_kernel<<<grid, block, 0, stream>>>(u, y0g, bog, ws, out);
}

// Round 10
// 339.980 us; speedup vs baseline: 1.0855x; 1.0855x over previous
//
#include <hip/hip_runtime.h>

#define T_HORIZON 50
#define NU 4
#define NY 4
#define KH 32
#define BPB 64                    // batch elements per block (each wave: all 64)

typedef float v2f __attribute__((ext_vector_type(2)));

// Tied packed FMA: a = w*x + a, dst IS src2 (%0 twice) -> no moves, no alias
// freedom. Same instruction r8 verified correct, minus the early-clobber.
#define PK_FMA_ACC(a, w, x) \
    asm("v_pk_fma_f32 %0, %1, %2, %0" : "+v"(a) : "s"(w), "v"(x))

__device__ __forceinline__ v2f fma2(v2f a, v2f b, v2f c) {
    return __builtin_elementwise_fma(a, b, c);
}

#define TANH_SCALE 2.88539008177792681472f

// Stage transposed weights into d_ws: ws[jg][i][k] = W_all[i][jg + 4k]
// i=0..7: Wh rows; i=8: bh; i=9: wor. 4*10*8 = 320 floats.
__global__ void stage_weights(const float* __restrict__ Whg,
                              const float* __restrict__ bhg,
                              const float* __restrict__ Wog,
                              float* __restrict__ ws) {
    int idx = threadIdx.x;
    if (idx < 320) {
        int jg = idx / 80, r = idx % 80, i = r / 8, k = r % 8;
        int j = jg + 4 * k;
        float v = (i < 8) ? Whg[i * KH + j] : (i == 8 ? bhg[j] : Wog[j]);
        ws[idx] = v;
    }
}

__global__ __launch_bounds__(256, 6) void rollout_kernel(
    const float* __restrict__ u,    // (B, 50, 4)
    const float* __restrict__ y0g,  // (B, 4)
    const float* __restrict__ bog,  // (1)
    const float* __restrict__ wsW,  // (4, 10, 8) staged
    float* __restrict__ out)        // (B, 50, 1)
{
    __shared__ __align__(16) float sOut[BPB * T_HORIZON];  // [b_local][t]
    __shared__ float sRed[2][4][BPB];                      // dbuf class partials

    const int tid  = threadIdx.x;
    const int lane = tid & 63;
    const int jg = __builtin_amdgcn_readfirstlane(tid >> 6);

    const float* wb = wsW + jg * 80;   // uniform base
    // Wave-uniform weight pairs -> SGPR pairs (src0 of the tied pk_fma).
    v2f wh2[8][4], wor2[4], bh2[4];
#pragma unroll
    for (int i = 0; i < 8; ++i)
#pragma unroll
        for (int p = 0; p < 4; ++p)
            wh2[i][p] = *(const v2f*)(wb + i * 8 + 2 * p);
#pragma unroll
    for (int p = 0; p < 4; ++p) {
        wor2[p] = *(const v2f*)(wb + 9 * 8 + 2 * p);
        bh2[p]  = *(const v2f*)(wb + 8 * 8 + 2 * p);   // stays SGPR; copied per use
    }
    const float bor = bog[0];          // uniform -> SGPR

    const v2f scale2 = {TANH_SCALE, TANH_SCALE};
    const v2f one2   = {1.0f, 1.0f};
    const v2f ntwo2  = {-2.0f, -2.0f};

    const int b = blockIdx.x * BPB + lane;
    const float4* ub = (const float4*)(u + (size_t)b * T_HORIZON * NU);
    float4 yv = *(const float4*)(y0g + (size_t)b * NY);
    // y-state as broadcast pairs (both halves equal) — VGPR operands of pk_fma.
    v2f py1 = {yv.x, yv.x}, py2 = {yv.y, yv.y}, py3 = {yv.z, yv.z}, py4 = {yv.w, yv.w};

    float4 un = ub[0];

    auto step = [&](int t, int buf) {
        float4 uc = un;
        if (t + 1 < T_HORIZON) un = ub[t + 1];

        v2f ux = {uc.x, uc.x}, uy = {uc.y, uc.y}, uz = {uc.z, uc.z}, uw = {uc.w, uc.w};

        float pcls = 0.0f;
#pragma unroll
        for (int p = 0; p < 4; ++p) {
            // identical element order to rounds 2/4/7/8: bh, u0..u3, y1..y4
            v2f a = bh2[p];              // SGPR pair -> 2 v_mov into VGPR pair
            PK_FMA_ACC(a, wh2[0][p], ux);
            PK_FMA_ACC(a, wh2[1][p], uy);
            PK_FMA_ACC(a, wh2[2][p], uz);
            PK_FMA_ACC(a, wh2[3][p], uw);
            PK_FMA_ACC(a, wh2[4][p], py1);
            PK_FMA_ACC(a, wh2[5][p], py2);
            PK_FMA_ACC(a, wh2[6][p], py3);
            PK_FMA_ACC(a, wh2[7][p], py4);

            // tanh cluster, per-element identical to rounds 2..9
            v2f s = a * scale2;
            float e0 = __builtin_amdgcn_exp2f(s.x);
            float e1 = __builtin_amdgcn_exp2f(s.y);
            v2f ep = v2f{e0, e1} + one2;
            v2f r  = {__builtin_amdgcn_rcpf(ep.x), __builtin_amdgcn_rcpf(ep.y)};
            v2f th = fma2(ntwo2, r, one2);
            v2f m  = th * wor2[p];
            pcls += m.x;   // k=2p   (j = jg+8p)
            pcls += m.y;   // k=2p+1 (j = jg+8p+4)
        }

        // Cross-wave class reduce: double-buffered, ONE barrier per step.
        sRed[buf][jg][lane] = pcls;
        __syncthreads();
        float c0 = sRed[buf][0][lane];
        float c1 = sRed[buf][1][lane];
        float c2 = sRed[buf][2][lane];
        float c3 = sRed[buf][3][lane];
        float partial = (c0 + c1) + (c2 + c3);
        float pred = bor + partial;

        if (jg == 0) sOut[lane * T_HORIZON + t] = pred;

        py4 = py3; py3 = py2; py2 = py1;   // renamed by the x2 unroll, no movs
        py1 = v2f{pred, pred};
    };

    for (int t = 0; t < T_HORIZON; t += 2) {   // T=50 even
        step(t, 0);
        step(t + 1, 1);
    }
    __syncthreads();

    // Coalesced flush: block's out region is contiguous 64*50 floats.
    const float4* s4 = (const float4*)sOut;
    float4* o4 = (float4*)(out + (size_t)blockIdx.x * BPB * T_HORIZON);
#pragma unroll
    for (int k = 0; k < 4; ++k) {
        int idx = k * 256 + tid;
        if (idx < (BPB * T_HORIZON) / 4) o4[idx] = s4[idx];
    }
}

extern "C" void kernel_launch(void* const* d_in, const int* in_sizes, int n_in,
                              void* d_out, int out_size, void* d_ws, size_t ws_size,
                              hipStream_t stream) {
    const float* u   = (const float*)d_in[0];
    const float* y0g = (const float*)d_in[1];
    const float* Whg = (const float*)d_in[2];
    const float* bhg = (const float*)d_in[3];
    const float* Wog = (const float*)d_in[4];
    const float* bog = (const float*)d_in[5];
    float* out = (float*)d_out;
    float* ws  = (float*)d_ws;    // 320 floats staged weights

    stage_weights<<<1, 320, 0, stream>>>(Whg, bhg, Wog, ws);

    const int B = in_sizes[1] / NY;          // 524288
    dim3 grid(B / BPB), block(256);
    rollout_kernel<<<grid, block, 0, stream>>>(u, y0g, bog, ws, out);
}